// Round 17
// baseline (208.272 us; speedup 1.0000x reference)
//
#include <hip/hip_runtime.h>
#include <math.h>

#define D_ 256
#define H_ 4
#define DH_ 64
#define NKT_ 16          // K/V tiles per (b,h): 1024/64
#define NT_ 16384        // total tokens
#define TPB_BITS 10      // tokens per batch = 1024
#define SCL2E_ 0.18033688011112042f   // 0.125 * log2(e)

typedef __attribute__((ext_vector_type(8))) short bf16x8;
typedef __attribute__((ext_vector_type(4))) short short4v;
typedef __attribute__((ext_vector_type(4))) float f32x4;

__device__ __forceinline__ short f2bf(float x) {
  union { float f; unsigned u; } c; c.f = x;
  unsigned r = (c.u + 0x7fffu + ((c.u >> 16) & 1u)) >> 16;
  return (short)r;
}
__device__ __forceinline__ float bf2f(short s) {
  union { unsigned u; float f; } c; c.u = ((unsigned)(unsigned short)s) << 16;
  return c.f;
}
__device__ __forceinline__ unsigned cvtpk(float lo, float hi) {
  unsigned r;
  asm("v_cvt_pk_bf16_f32 %0, %1, %2" : "=v"(r) : "v"(lo), "v"(hi));
  return r;
}
#if __has_builtin(__builtin_amdgcn_exp2f)
#define EXP2F(x) __builtin_amdgcn_exp2f(x)
#else
#define EXP2F(x) __expf(0.6931471805599453f * (x))
#endif

// global -> LDS direct copy, 16B per lane (dest = wave-uniform base + lane*16)
__device__ __forceinline__ void gl_lds16(const void* g, void* lds) {
  __builtin_amdgcn_global_load_lds((const __attribute__((address_space(1))) void*)g,
                                   (__attribute__((address_space(3))) void*)lds,
                                   16, 0, 0);
}

// ---------------------------------------------------------------------------
// mask -> additive softmax bias (0 / -1e30) + per-(b,kt) "has-masked" flags
// ---------------------------------------------------------------------------
__global__ __launch_bounds__(256) void mask_bias(const float* __restrict__ m0,
                                                 const float* __restrict__ m1,
                                                 float* __restrict__ o0,
                                                 float* __restrict__ o1,
                                                 float* __restrict__ f0,
                                                 float* __restrict__ f1, int n) {
  int i = blockIdx.x * 256 + threadIdx.x;
  if (i < n) {
    o0[i] = (m0[i] != 0.f) ? 0.f : -1e30f;
    o1[i] = (m1[i] != 0.f) ? 0.f : -1e30f;
  }
  if (blockIdx.x == 0) {    // 256 threads = B*NKT flags, reads ORIGINAL masks
    int t = threadIdx.x;
    const float* ms = m0 + (t >> 4) * 1024 + (t & 15) * 64;
    const float* mc = m1 + (t >> 4) * 1024 + (t & 15) * 64;
    float fs = 0.f, fc = 0.f;
    for (int j = 0; j < 64; ++j) {
      if (ms[j] == 0.f) fs = 1.f;
      if (mc[j] == 0.f) fc = 1.f;
    }
    f0[t] = fs; f1[t] = fc;
  }
}

// ---------------------------------------------------------------------------
// MFMA GEMM, double-buffered LDS, fused multi-op via blockIdx.z.
// C[N,M] = A[N,K] * (TRANSB ? B^T : B), optional ReLU. 128 x BN tile.
// BK=32 (stride 40, 41KB -> 4 blocks/CU, BN=128) or BK=64 (stride 72, BN=64).
// ---------------------------------------------------------------------------
template<int BN, int BK, bool ABF16, bool TRANSB, bool RELU, bool CBF16>
__global__ __launch_bounds__(256) void gemm_mfma(
    const void* __restrict__ A0, const void* __restrict__ A1, const void* __restrict__ A2,
    const float* __restrict__ B0, const float* __restrict__ B1, const float* __restrict__ B2,
    void* __restrict__ C0, void* __restrict__ C1, void* __restrict__ C2,
    int N, int K, int M, int vtrans_z, int ktile_z, int abf16_z, int qscale_z) {
  constexpr int STR = BK + 8;
  __shared__ short Al[2][128][STR];
  __shared__ short Bl[2][BN][STR];
  const int tid = threadIdx.x;
  const int w   = tid >> 6;
  const int l   = tid & 63;
  const int bn  = blockIdx.x * 128;
  const int bm  = blockIdx.y * BN;
  const int z   = blockIdx.z;
  const void*  Av = (z == 0) ? A0 : ((z == 1) ? A1 : A2);
  const float* B  = (z == 0) ? B0 : ((z == 1) ? B1 : B2);
  void*        Cv = (z == 0) ? C0 : ((z == 1) ? C1 : C2);
  const bool abf = ABF16 || (z == abf16_z);
  constexpr int NI = BN / 32;
  const int wm = (w >> 1) * 64;
  const int wn = (w & 1) * (BN / 2);
  const int fr = l & 15;
  const int fg = l >> 4;

  f32x4 acc[4][NI];
  #pragma unroll
  for (int mi = 0; mi < 4; ++mi)
    #pragma unroll
    for (int ni = 0; ni < NI; ++ni) acc[mi][ni] = (f32x4){0.f, 0.f, 0.f, 0.f};

  const int sr = tid >> 1;
  const int sc = (tid & 1) * (BK / 2);
  constexpr int ARF = BK / 8;
  constexpr int ARB = BK / 16;
  constexpr int BRF = (BN == 128) ? (BK / 8) : (BK / 16);
  const int brT = (BN == 128) ? (tid >> 1) : (tid >> 2);
  const int bcT = (BN == 128) ? ((tid & 1) * (BK / 2)) : ((tid & 3) * (BK / 4));

  float4 arf[ARF]; bf16x8 arb[ARB]; float4 brf[BRF > ARF ? BRF : ARF];

  auto loadA = [&](int k0) {
    if (abf) {
      const short* arow = (const short*)Av + (size_t)(bn + sr) * K + k0 + sc;
      #pragma unroll
      for (int i = 0; i < ARB; ++i) arb[i] = *(const bf16x8*)&arow[i * 8];
    } else {
      const float* arow = (const float*)Av + (size_t)(bn + sr) * K + k0 + sc;
      #pragma unroll
      for (int i = 0; i < ARF; ++i) arf[i] = *(const float4*)&arow[i * 4];
    }
  };
  auto loadB = [&](int k0) {
    if (TRANSB) {
      const float* brow = B + (size_t)(bm + brT) * K + k0 + bcT;
      #pragma unroll
      for (int i = 0; i < BRF; ++i) brf[i] = *(const float4*)&brow[i * 4];
    } else {
      #pragma unroll
      for (int i = 0; i < BRF; ++i) {
        int idx = tid + i * 256;
        int kk = (BN == 128) ? (idx >> 5) : (idx >> 4);
        int c4 = (BN == 128) ? ((idx & 31) * 4) : ((idx & 15) * 4);
        brf[i] = *(const float4*)&B[(size_t)(k0 + kk) * M + bm + c4];
      }
    }
  };
  auto store = [&](int buf) {
    if (abf) {
      #pragma unroll
      for (int i = 0; i < ARB; ++i) *(bf16x8*)&Al[buf][sr][sc + i * 8] = arb[i];
    } else {
      #pragma unroll
      for (int i = 0; i < ARF; ++i) {
        float4 v = arf[i];
        short4v s; s[0] = f2bf(v.x); s[1] = f2bf(v.y); s[2] = f2bf(v.z); s[3] = f2bf(v.w);
        *(short4v*)&Al[buf][sr][sc + i * 4] = s;
      }
    }
    if (TRANSB) {
      #pragma unroll
      for (int i = 0; i < BRF; ++i) {
        float4 v = brf[i];
        short4v s; s[0] = f2bf(v.x); s[1] = f2bf(v.y); s[2] = f2bf(v.z); s[3] = f2bf(v.w);
        *(short4v*)&Bl[buf][brT][bcT + i * 4] = s;
      }
    } else {
      #pragma unroll
      for (int i = 0; i < BRF; ++i) {
        int idx = tid + i * 256;
        int kk = (BN == 128) ? (idx >> 5) : (idx >> 4);
        int c4 = (BN == 128) ? ((idx & 31) * 4) : ((idx & 15) * 4);
        float4 v = brf[i];
        Bl[buf][c4 + 0][kk] = f2bf(v.x);
        Bl[buf][c4 + 1][kk] = f2bf(v.y);
        Bl[buf][c4 + 2][kk] = f2bf(v.z);
        Bl[buf][c4 + 3][kk] = f2bf(v.w);
      }
    }
  };

  loadA(0); loadB(0); store(0);
  __syncthreads();
  const int nk = K / BK;
  for (int s = 0; s < nk; ++s) {
    const int cur = s & 1;
    if (s + 1 < nk) { loadA((s + 1) * BK); loadB((s + 1) * BK); }
    #pragma unroll
    for (int kh = 0; kh < BK / 32; ++kh) {
      bf16x8 af[4], bfr[NI];
      #pragma unroll
      for (int mi = 0; mi < 4; ++mi)
        af[mi] = *(bf16x8*)&Al[cur][wm + mi * 16 + fr][kh * 32 + fg * 8];
      #pragma unroll
      for (int ni = 0; ni < NI; ++ni)
        bfr[ni] = *(bf16x8*)&Bl[cur][wn + ni * 16 + fr][kh * 32 + fg * 8];
      #pragma unroll
      for (int mi = 0; mi < 4; ++mi)
        #pragma unroll
        for (int ni = 0; ni < NI; ++ni)
          acc[mi][ni] = __builtin_amdgcn_mfma_f32_16x16x32_bf16(af[mi], bfr[ni], acc[mi][ni], 0, 0, 0);
    }
    if (s + 1 < nk) store(cur ^ 1);
    __syncthreads();
  }

  bool done = false;
  if constexpr (BN == 128) {
    if (z == vtrans_z) {
      done = true;
      // V-tiled: [bh][kt][d=64][k=64], granule16 col ^= (d&7). uint2 spans k..k+3.
      #pragma unroll
      for (int mi = 0; mi < 4; ++mi) {
        int nbase = bn + wm + mi * 16 + fg * 4;
        int b_  = nbase >> TPB_BITS;
        int key = nbase & ((1 << TPB_BITS) - 1);
        int kt  = key >> 6, kin = key & 63;
        #pragma unroll
        for (int ni = 0; ni < 4; ++ni) {
          int col = bm + wn + ni * 16 + fr;
          int h_ = col >> 6, dh = col & 63;
          uint2 u;
          u.x = cvtpk(acc[mi][ni][0], acc[mi][ni][1]);
          u.y = cvtpk(acc[mi][ni][2], acc[mi][ni][3]);
          size_t off = ((((size_t)(b_ * H_ + h_) * NKT_) + kt) << 12)
                     + dh * 64 + (((kin >> 3) ^ (dh & 7)) << 3) + (kin & 7);
          *(uint2*)&((short*)Cv)[off] = u;
        }
      }
    } else if (z == ktile_z) {
      done = true;
      // K-tiled: [bh][kt][k=64][d=64], granule16 col ^= (k&3)|((k>>3)&1)<<2.
      #pragma unroll
      for (int mi = 0; mi < 4; ++mi) {
        #pragma unroll
        for (int reg = 0; reg < 4; ++reg) {
          int tok = bn + wm + mi * 16 + fg * 4 + reg;
          int b_  = tok >> TPB_BITS;
          int key = tok & ((1 << TPB_BITS) - 1);
          int kt  = key >> 6, kin = key & 63;
          int fk  = (kin & 3) | (((kin >> 3) & 1) << 2);
          size_t tb = ((((size_t)(b_ * H_) * NKT_) + kt) << 12) + kin * 64;
          #pragma unroll
          for (int ni = 0; ni < 4; ++ni) {
            int col = bm + wn + ni * 16 + fr;
            int h_ = col >> 6, dh = col & 63;
            size_t off = tb + (((size_t)h_ * NKT_) << 12)
                       + (((dh >> 3) ^ fk) << 3) + (dh & 7);
            ((short*)Cv)[off] = f2bf(acc[mi][ni][reg]);
          }
        }
      }
    }
  }
  if (!done) {
    const float cs = (z == qscale_z) ? SCL2E_ : 1.f;
    #pragma unroll
    for (int mi = 0; mi < 4; ++mi) {
      #pragma unroll
      for (int reg = 0; reg < 4; ++reg) {
        size_t rowbase = (size_t)(bn + wm + mi * 16 + fg * 4 + reg) * M + bm + wn;
        #pragma unroll
        for (int ni = 0; ni < NI; ++ni) {
          float v = acc[mi][ni][reg] * cs;
          if (RELU) v = fmaxf(v, 0.f);
          if (CBF16) ((short*)Cv)[rowbase + ni * 16 + fr] = f2bf(v);
          else       ((float*)Cv)[rowbase + ni * 16 + fr] = v;
        }
      }
    }
  }
}

// ---------------------------------------------------------------------------
// Split-K bf16 MFMA flash attention. blockIdx.z in {0,1} picks the kt half;
// single-buffered K/V LDS (16 KB) -> 8 blocks/CU resident (TLP hides staging).
// Writes unnormalized bf16 partial O + per-row (m, ls) stats (log2 domain);
// attn_merge recombines. CAUSAL: qt = last - by; z=1 empty when qt < 8.
// ---------------------------------------------------------------------------
template<bool CAUSAL>
__global__ __launch_bounds__(256) void attn_mfma(const short* __restrict__ Q,
                                                 const short* __restrict__ KT,
                                                 const short* __restrict__ VT,
                                                 const float* __restrict__ bias,
                                                 const float* __restrict__ flags,
                                                 short* __restrict__ Pp,
                                                 float2* __restrict__ st,
                                                 int T, int Lk) {
  __shared__ short Kl[64][64];
  __shared__ short Vl[64][64];
  const int tid = threadIdx.x;
  const int l   = tid & 63;
  const int w   = tid >> 6;
  const int bh  = blockIdx.x;
  const int b   = bh >> 2;
  const int h   = bh & 3;
  const int z   = blockIdx.z;
  const int r   = l & 15;
  const int g   = l >> 4;

  const short* Ktile = KT + (((size_t)bh * (Lk >> 6)) << 12);
  const short* Vtile = VT + (((size_t)bh * (Lk >> 6)) << 12);
  const float* brow  = bias + (size_t)b * Lk;
  const float* bfl   = flags + b * NKT_;

  const int qt   = CAUSAL ? ((T >> 6) - 1 - (int)blockIdx.y) : (int)blockIdx.y;
  const int full = CAUSAL ? (qt + 1) : (Lk >> 6);
  const int kt0  = z ? 8 : 0;
  const int kt1  = z ? full : (full < 8 ? full : 8);

  float m = -1e30f, ls = 0.f;

  if (kt1 <= kt0) {   // empty half: stats only (ls=0 -> merge weight 0)
    if (l < 16)
      st[((size_t)z * 64 + bh) * 1024 + qt * 64 + w * 16 + l] = make_float2(m, ls);
    return;
  }

  bf16x8 qf[2];
  {
    const short* qrow = Q + ((size_t)(b * T + qt * 64 + w * 16 + r)) * D_ + h * DH_;
    qf[0] = *(const bf16x8*)&qrow[g * 8];
    qf[1] = *(const bf16x8*)&qrow[32 + g * 8];
  }

  f32x4 acc[4];
  #pragma unroll
  for (int dt = 0; dt < 4; ++dt) acc[dt] = (f32x4){0.f, 0.f, 0.f, 0.f};

  auto stage = [&](int kt) {
    const short* ks = Ktile + ((size_t)kt << 12) + w * 1024 + (size_t)l * 8;
    const short* vs = Vtile + ((size_t)kt << 12) + w * 1024 + (size_t)l * 8;
    char* kd = (char*)&Kl[0][0] + w * 2048;
    char* vd = (char*)&Vl[0][0] + w * 2048;
    gl_lds16(ks,       kd);
    gl_lds16(ks + 512, kd + 1024);
    gl_lds16(vs,       vd);
    gl_lds16(vs + 512, vd + 1024);
  };

  const int rx = r & 7;
  const int rowp = 8 * (r >> 2) + (r & 3);
  const char* kb = (const char*)&Kl[0][0];
  const char* vb = (const char*)&Vl[0][0];

  for (int kt = kt0; kt < kt1; ++kt) {
    if (kt > kt0) __syncthreads();   // all reads of prev tile done
    stage(kt);
    __syncthreads();                 // drains vmcnt: tile visible

    // ---- swapped QK^T, k-remapped sub-tiles (Q pre-scaled: log2-domain) ----
    f32x4 sfr[4];
    #pragma unroll
    for (int stt = 0; stt < 4; ++stt) sfr[stt] = (f32x4){0.f, 0.f, 0.f, 0.f};
    __builtin_amdgcn_s_setprio(1);
    #pragma unroll
    for (int stt = 0; stt < 4; ++stt) {
      const int rowk = 32 * (stt >> 1) + 4 * (stt & 1) + rowp;
      #pragma unroll
      for (int kh = 0; kh < 2; ++kh) {
        bf16x8 kf = *(const bf16x8*)(kb + rowk * 128 + (((kh * 4 + g) ^ rx) << 4));
        sfr[stt] = __builtin_amdgcn_mfma_f32_16x16x32_bf16(kf, qf[kh], sfr[stt], 0, 0, 0);
      }
    }
    __builtin_amdgcn_s_setprio(0);

    // ---- bias only when tile has masked keys (wave-uniform branch) ----
    float sc[4][4];
    if (bfl[kt] != 0.f) {
      #pragma unroll
      for (int stt = 0; stt < 4; ++stt) {
        float4 mv = *(const float4*)&brow[kt * 64 + 32 * (stt >> 1) + 4 * (stt & 1) + 8 * g];
        sc[stt][0] = sfr[stt][0] + mv.x;
        sc[stt][1] = sfr[stt][1] + mv.y;
        sc[stt][2] = sfr[stt][2] + mv.z;
        sc[stt][3] = sfr[stt][3] + mv.w;
      }
    } else {
      #pragma unroll
      for (int stt = 0; stt < 4; ++stt)
        #pragma unroll
        for (int reg = 0; reg < 4; ++reg) sc[stt][reg] = sfr[stt][reg];
    }
    if (CAUSAL && kt == qt) {
      #pragma unroll
      for (int stt = 0; stt < 4; ++stt)
        #pragma unroll
        for (int reg = 0; reg < 4; ++reg)
          if (32 * (stt >> 1) + 4 * (stt & 1) + 8 * g + reg > w * 16 + r)
            sc[stt][reg] = -1e30f;
    }

    // ---- row max via max3 triples ----
    float t0 = fmaxf(fmaxf(sc[0][0], sc[0][1]), sc[0][2]);
    float t1 = fmaxf(fmaxf(sc[0][3], sc[1][0]), sc[1][1]);
    float t2 = fmaxf(fmaxf(sc[1][2], sc[1][3]), sc[2][0]);
    float t3 = fmaxf(fmaxf(sc[2][1], sc[2][2]), sc[2][3]);
    float t4 = fmaxf(fmaxf(sc[3][0], sc[3][1]), sc[3][2]);
    float tm = fmaxf(fmaxf(fmaxf(t0, t1), fmaxf(t2, t3)), fmaxf(t4, sc[3][3]));
    tm = fmaxf(tm, __shfl_xor(tm, 16));
    tm = fmaxf(tm, __shfl_xor(tm, 32));
    const int need = __any(tm - m > 8.f);
    float mnew = need ? fmaxf(m, tm) : m;
    float pe[4][4];
    #pragma unroll
    for (int stt = 0; stt < 4; ++stt)
      #pragma unroll
      for (int reg = 0; reg < 4; ++reg)
        pe[stt][reg] = EXP2F(sc[stt][reg] - mnew);
    float ps0 = (pe[0][0] + pe[0][1]) + (pe[0][2] + pe[0][3]);
    float ps1 = (pe[1][0] + pe[1][1]) + (pe[1][2] + pe[1][3]);
    float ps2 = (pe[2][0] + pe[2][1]) + (pe[2][2] + pe[2][3]);
    float ps3 = (pe[3][0] + pe[3][1]) + (pe[3][2] + pe[3][3]);
    float psum = (ps0 + ps1) + (ps2 + ps3);
    psum += __shfl_xor(psum, 16);
    psum += __shfl_xor(psum, 32);

    // ---- P -> A-frag entirely in registers ----
    union { unsigned u[4]; bf16x8 v; } pa, pb;
    pa.u[0] = cvtpk(pe[0][0], pe[0][1]);
    pa.u[1] = cvtpk(pe[0][2], pe[0][3]);
    pa.u[2] = cvtpk(pe[1][0], pe[1][1]);
    pa.u[3] = cvtpk(pe[1][2], pe[1][3]);
    pb.u[0] = cvtpk(pe[2][0], pe[2][1]);
    pb.u[1] = cvtpk(pe[2][2], pe[2][3]);
    pb.u[2] = cvtpk(pe[3][0], pe[3][1]);
    pb.u[3] = cvtpk(pe[3][2], pe[3][3]);

    if (need) {
      float alpha = EXP2F(m - mnew);
      ls = ls * alpha + psum;
      m = mnew;
      float af[4];
      #pragma unroll
      for (int reg = 0; reg < 4; ++reg) af[reg] = __shfl(alpha, g * 4 + reg);
      #pragma unroll
      for (int dt = 0; dt < 4; ++dt)
        #pragma unroll
        for (int reg = 0; reg < 4; ++reg) acc[dt][reg] *= af[reg];
    } else {
      ls += psum;
    }

    // ---- PV ----
    __builtin_amdgcn_s_setprio(1);
    #pragma unroll
    for (int kh = 0; kh < 2; ++kh) {
      bf16x8 pf = (kh == 0) ? pa.v : pb.v;
      #pragma unroll
      for (int dt = 0; dt < 4; ++dt) {
        bf16x8 vf = *(const bf16x8*)(vb + (dt * 16 + r) * 128 + (((kh * 4 + g) ^ rx) << 4));
        acc[dt] = __builtin_amdgcn_mfma_f32_16x16x32_bf16(pf, vf, acc[dt], 0, 0, 0);
      }
    }
    __builtin_amdgcn_s_setprio(0);
  }

  // ---- epilogue: unnormalized bf16 partial + stats ----
  short* pbase = Pp + (size_t)z * ((size_t)NT_ * 256);
  #pragma unroll
  for (int reg = 0; reg < 4; ++reg) {
    short* prow = pbase + ((size_t)(b * T + qt * 64 + w * 16 + g * 4 + reg)) * D_ + h * DH_;
    #pragma unroll
    for (int dt = 0; dt < 4; ++dt)
      prow[dt * 16 + r] = f2bf(acc[dt][reg]);
  }
  if (l < 16)
    st[((size_t)z * 64 + bh) * 1024 + qt * 64 + w * 16 + l] = make_float2(m, ls);
}

// ---------------------------------------------------------------------------
// merge split-K halves: O = (a0*acc0 + a1*acc1) / (a0*ls0 + a1*ls1)
// ---------------------------------------------------------------------------
__global__ __launch_bounds__(256) void attn_merge(const short* __restrict__ P,
                                                  const float2* __restrict__ st,
                                                  short* __restrict__ O) {
  const int lane = threadIdx.x & 63;
  const int wid  = threadIdx.x >> 6;
  const int row  = blockIdx.x * 4 + wid;       // b*1024 + q
  const int b    = row >> TPB_BITS;
  const int q    = row & ((1 << TPB_BITS) - 1);
  const int h    = lane >> 4;
  const int bh   = b * H_ + h;
  float2 s0 = st[(size_t)bh * 1024 + q];
  float2 s1 = st[(size_t)(64 + bh) * 1024 + q];
  float mm = fmaxf(s0.x, s1.x);
  float a0 = EXP2F(s0.x - mm), a1 = EXP2F(s1.x - mm);
  float den = a0 * s0.y + a1 * s1.y;
  float inv = (den > 0.f) ? (1.f / den) : 0.f;
  a0 *= inv; a1 *= inv;
  size_t base = (size_t)row * 256 + (size_t)lane * 4;
  short4v p0 = *(const short4v*)&P[base];
  short4v p1 = *(const short4v*)&P[(size_t)NT_ * 256 + base];
  uint2 u;
  u.x = cvtpk(a0 * bf2f(p0[0]) + a1 * bf2f(p1[0]),
              a0 * bf2f(p0[1]) + a1 * bf2f(p1[1]));
  u.y = cvtpk(a0 * bf2f(p0[2]) + a1 * bf2f(p1[2]),
              a0 * bf2f(p0[3]) + a1 * bf2f(p1[3]));
  *(uint2*)&O[base] = u;
}

// ---------------------------------------------------------------------------
// out[row] = R[row] + LayerNorm(F[row]) * g + b   (row length 256, F bf16)
// ---------------------------------------------------------------------------
template<bool RBF16, bool OBF16>
__global__ __launch_bounds__(256) void ln_res(const short* __restrict__ F,
                                              const void* __restrict__ Rv,
                                              const float* __restrict__ g,
                                              const float* __restrict__ bt,
                                              void* __restrict__ outv) {
  const int lane = threadIdx.x & 63;
  const int wid  = threadIdx.x >> 6;
  const size_t row  = (size_t)blockIdx.x * 4 + wid;
  const size_t base = row * 256 + (size_t)lane * 4;
  short4v fv = *(const short4v*)&F[base];
  float vx = bf2f(fv[0]), vy = bf2f(fv[1]), vz = bf2f(fv[2]), vw = bf2f(fv[3]);
  float s = vx + vy + vz + vw;
  #pragma unroll
  for (int o = 32; o >= 1; o >>= 1) s += __shfl_xor(s, o);
  float mu = s * (1.f / 256.f);
  float dx = vx - mu, dy = vy - mu, dz = vz - mu, dw = vw - mu;
  float vr = dx * dx + dy * dy + dz * dz + dw * dw;
  #pragma unroll
  for (int o = 32; o >= 1; o >>= 1) vr += __shfl_xor(vr, o);
  float rstd = rsqrtf(vr * (1.f / 256.f) + 1e-5f);
  float4 g4 = *(const float4*)&g[lane * 4];
  float4 b4 = *(const float4*)&bt[lane * 4];
  float rx, ry, rz, rw;
  if (RBF16) {
    short4v r4 = *(const short4v*)&((const short*)Rv)[base];
    rx = bf2f(r4[0]); ry = bf2f(r4[1]); rz = bf2f(r4[2]); rw = bf2f(r4[3]);
  } else {
    float4 r4 = *(const float4*)&((const float*)Rv)[base];
    rx = r4.x; ry = r4.y; rz = r4.z; rw = r4.w;
  }
  float ox = fmaf(dx * rstd, g4.x, b4.x) + rx;
  float oy = fmaf(dy * rstd, g4.y, b4.y) + ry;
  float oz = fmaf(dz * rstd, g4.z, b4.z) + rz;
  float ow = fmaf(dw * rstd, g4.w, b4.w) + rw;
  if (OBF16) {
    uint2 u; u.x = cvtpk(ox, oy); u.y = cvtpk(oz, ow);
    *(uint2*)&((short*)outv)[base] = u;
  } else {
    *(float4*)&((float*)outv)[base] = make_float4(ox, oy, oz, ow);
  }
}

extern "C" void kernel_launch(void* const* d_in, const int* in_sizes, int n_in,
                              void* d_out, int out_size, void* d_ws, size_t ws_size,
                              hipStream_t stream) {
  const float* Xt    = (const float*)d_in[0];
  const float* oMask = (const float*)d_in[1];
  const float* Xe    = (const float*)d_in[2];
  const float* iMask = (const float*)d_in[3];
  const float* Wq1   = (const float*)d_in[4];
  const float* Wk1   = (const float*)d_in[5];
  const float* Wv1   = (const float*)d_in[6];
  const float* Wo1   = (const float*)d_in[7];
  const float* Wq2   = (const float*)d_in[8];
  const float* Wk2   = (const float*)d_in[9];
  const float* Wv2   = (const float*)d_in[10];
  const float* Wo2   = (const float*)d_in[11];
  const float* W1    = (const float*)d_in[12];
  const float* W2    = (const float*)d_in[13];
  const float* g1    = (const float*)d_in[14];
  const float* b1    = (const float*)d_in[15];
  const float* g2    = (const float*)d_in[16];
  const float* b2    = (const float*)d_in[17];
  const float* g3    = (const float*)d_in[18];
  const float* b3    = (const float*)d_in[19];

  const int B = 16, T = 1024, S = 1024;
  const int NT = B * T;
  const size_t SZ = (size_t)NT * 256;   // fp32-sized slot

  float* ws = (float*)d_ws;
  float* s0 = ws;                // Q bf16 / FFN H bf16 (spans s0..s1) / Wo out bf16
  float* s1 = ws + SZ;           // K tiled bf16
  float* s2 = ws + 2 * SZ;       // V tiled bf16
  float* s3 = ws + 3 * SZ;       // merged attn O bf16 (8MB) + bias/flags/stats tail
  float* s4 = ws + 4 * SZ;       // Xa bf16 / F bf16
  float* s5 = ws + 5 * SZ;       // split-K partials (16MB) -> later Xb bf16
  short* b_s0 = (short*)s0; short* b_s3 = (short*)s3;
  short* b_s4 = (short*)s4; short* b_s5 = (short*)s5;
  float* biasS = s3 + 3 * (SZ / 4);            // 12MB into s3 slot
  float* biasC = biasS + B * S;
  float* flagS = biasC + B * S;
  float* flagC = flagS + B * NKT_;
  float2* stat = (float2*)(flagC + B * NKT_);  // 1MB, reused by both attns

  dim3 blk(256);
  dim3 gQKV(NT / 128, 2, 3);     // fused q/k/v (BK=32 -> 4 blocks/CU)
  dim3 gS64(NT / 128, 4, 1);     // BN=64 singles -> 512 blocks
  dim3 gF1(NT / 128, 8, 1);      // FFN1 (BK=32)
  dim3 gA(B * H_, T / 64, 2);    // split-K attention: 2048 blocks = 8/CU
  dim3 gM(NT / 4);

  mask_bias<<<64, blk, 0, stream>>>(oMask, iMask, biasS, biasC, flagS, flagC, B * T);

  // ---- self-attention block ----
  gemm_mfma<128, 32, false, true, false, true><<<gQKV, blk, 0, stream>>>(
      Xt, Xt, Xt, Wq1, Wk1, Wv1, s0, s1, s2, NT, 256, 256, 2, 1, -1, 0);
  attn_mfma<true><<<gA, blk, 0, stream>>>((const short*)s0, (const short*)s1, (const short*)s2,
                                          biasS, flagS, b_s5, stat, T, T);
  attn_merge<<<gM, blk, 0, stream>>>(b_s5, stat, b_s3);
  gemm_mfma<64, 64, true, true, false, true><<<gS64, blk, 0, stream>>>(
      s3, s3, s3, Wo1, Wo1, Wo1, s0, s0, s0, NT, 256, 256, -1, -1, -1, -1);
  ln_res<false, true><<<gM, blk, 0, stream>>>(b_s0, Xt, g1, b1, b_s4);

  // ---- cross-attention block (Q2 merged into K/V fused launch) ----
  gemm_mfma<128, 32, false, true, false, true><<<gQKV, blk, 0, stream>>>(
      s4, Xe, Xe, Wq2, Wk2, Wv2, s0, s1, s2, NT, 256, 256, 2, 1, 0, 0);
  attn_mfma<false><<<gA, blk, 0, stream>>>((const short*)s0, (const short*)s1, (const short*)s2,
                                           biasC, flagC, b_s5, stat, T, S);
  attn_merge<<<gM, blk, 0, stream>>>(b_s5, stat, b_s3);
  gemm_mfma<64, 64, true, false, false, true><<<gS64, blk, 0, stream>>>(
      s3, s3, s3, Wo2, Wo2, Wo2, s0, s0, s0, NT, 256, 256, -1, -1, -1, -1);
  ln_res<true, true><<<gM, blk, 0, stream>>>(b_s0, b_s4, g2, b2, b_s5);

  // ---- FFN ----  (H bf16 spans s0..s1)
  gemm_mfma<128, 32, true, true, true, true><<<gF1, blk, 0, stream>>>(
      s5, s5, s5, W1, W1, W1, s0, s0, s0, NT, 256, 1024, -1, -1, -1, -1);
  gemm_mfma<64, 64, true, true, true, true><<<gS64, blk, 0, stream>>>(
      s0, s0, s0, W2, W2, W2, s4, s4, s4, NT, 1024, 256, -1, -1, -1, -1);
  ln_res<true, false><<<gM, blk, 0, stream>>>(b_s4, b_s5, g3, b3, (float*)d_out);
}

// Round 18
// 197.318 us; speedup vs baseline: 1.0555x; 1.0555x over previous
//
#include <hip/hip_runtime.h>
#include <math.h>

#define D_ 256
#define H_ 4
#define DH_ 64
#define NKT_ 16          // K/V tiles per (b,h): 1024/64
#define TPB_BITS 10      // tokens per batch = 1024
#define SCL2E_ 0.18033688011112042f   // 0.125 * log2(e)

typedef __attribute__((ext_vector_type(8))) short bf16x8;
typedef __attribute__((ext_vector_type(4))) short short4v;
typedef __attribute__((ext_vector_type(4))) float f32x4;

__device__ __forceinline__ short f2bf(float x) {
  union { float f; unsigned u; } c; c.f = x;
  unsigned r = (c.u + 0x7fffu + ((c.u >> 16) & 1u)) >> 16;
  return (short)r;
}
__device__ __forceinline__ float bf2f(short s) {
  union { unsigned u; float f; } c; c.u = ((unsigned)(unsigned short)s) << 16;
  return c.f;
}
__device__ __forceinline__ unsigned cvtpk(float lo, float hi) {
  unsigned r;
  asm("v_cvt_pk_bf16_f32 %0, %1, %2" : "=v"(r) : "v"(lo), "v"(hi));
  return r;
}
#if __has_builtin(__builtin_amdgcn_exp2f)
#define EXP2F(x) __builtin_amdgcn_exp2f(x)
#else
#define EXP2F(x) __expf(0.6931471805599453f * (x))
#endif

// global -> LDS direct copy, 16B per lane (dest = wave-uniform base + lane*16)
__device__ __forceinline__ void gl_lds16(const void* g, void* lds) {
  __builtin_amdgcn_global_load_lds((const __attribute__((address_space(1))) void*)g,
                                   (__attribute__((address_space(3))) void*)lds,
                                   16, 0, 0);
}

// ---------------------------------------------------------------------------
// mask -> additive softmax bias (0 / -1e30) + per-(b,kt) "has-masked" flags
// ---------------------------------------------------------------------------
__global__ __launch_bounds__(256) void mask_bias(const float* __restrict__ m0,
                                                 const float* __restrict__ m1,
                                                 float* __restrict__ o0,
                                                 float* __restrict__ o1,
                                                 float* __restrict__ f0,
                                                 float* __restrict__ f1, int n) {
  int i = blockIdx.x * 256 + threadIdx.x;
  if (i < n) {
    o0[i] = (m0[i] != 0.f) ? 0.f : -1e30f;
    o1[i] = (m1[i] != 0.f) ? 0.f : -1e30f;
  }
  if (blockIdx.x == 0) {    // 256 threads = B*NKT flags, reads ORIGINAL masks
    int t = threadIdx.x;
    const float* ms = m0 + (t >> 4) * 1024 + (t & 15) * 64;
    const float* mc = m1 + (t >> 4) * 1024 + (t & 15) * 64;
    float fs = 0.f, fc = 0.f;
    for (int j = 0; j < 64; ++j) {
      if (ms[j] == 0.f) fs = 1.f;
      if (mc[j] == 0.f) fc = 1.f;
    }
    f0[t] = fs; f1[t] = fc;
  }
}

// ---------------------------------------------------------------------------
// MFMA GEMM, double-buffered LDS, fused multi-op via blockIdx.z.
// C[N,M] = A[N,K] * (TRANSB ? B^T : B), optional ReLU. 128 x BN tile.
// BK template: 32 (stride 40 shorts, 41KB LDS -> 4 blocks/CU for BN=128
// fused launches) or 64 (stride 72, R11-proven, used for BN=64 singles).
// abf16_z: treat A as bf16 for that z even when ABF16=false (mixed fusion).
// qscale_z: multiply C by SCL2E_ for that z (Q pre-scaling).
// z==vtrans_z (BN=128): C -> V-tiled [bh][kt][64d][64k] bf16, granule ^= d&7.
// z==ktile_z  (BN=128): C -> K-tiled [bh][kt][64k][64d] bf16,
//                       granule ^= (k&3)|((k>>3)&1)<<2  (P-in-reg k-remap).
// ---------------------------------------------------------------------------
template<int BN, int BK, bool ABF16, bool TRANSB, bool RELU, bool CBF16>
__global__ __launch_bounds__(256) void gemm_mfma(
    const void* __restrict__ A0, const void* __restrict__ A1, const void* __restrict__ A2,
    const float* __restrict__ B0, const float* __restrict__ B1, const float* __restrict__ B2,
    void* __restrict__ C0, void* __restrict__ C1, void* __restrict__ C2,
    int N, int K, int M, int vtrans_z, int ktile_z, int abf16_z, int qscale_z) {
  constexpr int STR = BK + 8;
  __shared__ short Al[2][128][STR];
  __shared__ short Bl[2][BN][STR];
  const int tid = threadIdx.x;
  const int w   = tid >> 6;
  const int l   = tid & 63;
  const int bn  = blockIdx.x * 128;
  const int bm  = blockIdx.y * BN;
  const int z   = blockIdx.z;
  const void*  Av = (z == 0) ? A0 : ((z == 1) ? A1 : A2);
  const float* B  = (z == 0) ? B0 : ((z == 1) ? B1 : B2);
  void*        Cv = (z == 0) ? C0 : ((z == 1) ? C1 : C2);
  const bool abf = ABF16 || (z == abf16_z);
  constexpr int NI = BN / 32;
  const int wm = (w >> 1) * 64;
  const int wn = (w & 1) * (BN / 2);
  const int fr = l & 15;
  const int fg = l >> 4;

  f32x4 acc[4][NI];
  #pragma unroll
  for (int mi = 0; mi < 4; ++mi)
    #pragma unroll
    for (int ni = 0; ni < NI; ++ni) acc[mi][ni] = (f32x4){0.f, 0.f, 0.f, 0.f};

  // A staging: 2 threads/row, each BK/2 elems
  const int sr = tid >> 1;
  const int sc = (tid & 1) * (BK / 2);
  constexpr int ARF = BK / 8;    // fp32 float4 per thread
  constexpr int ARB = BK / 16;   // bf16x8 per thread
  // B staging (TRANSB): 256/BN threads per row
  constexpr int BRF = (BN == 128) ? (BK / 8) : (BK / 16);
  const int brT = (BN == 128) ? (tid >> 1) : (tid >> 2);
  const int bcT = (BN == 128) ? ((tid & 1) * (BK / 2)) : ((tid & 3) * (BK / 4));

  float4 arf[ARF]; bf16x8 arb[ARB]; float4 brf[BRF > ARF ? BRF : ARF];

  auto loadA = [&](int k0) {
    if (abf) {
      const short* arow = (const short*)Av + (size_t)(bn + sr) * K + k0 + sc;
      #pragma unroll
      for (int i = 0; i < ARB; ++i) arb[i] = *(const bf16x8*)&arow[i * 8];
    } else {
      const float* arow = (const float*)Av + (size_t)(bn + sr) * K + k0 + sc;
      #pragma unroll
      for (int i = 0; i < ARF; ++i) arf[i] = *(const float4*)&arow[i * 4];
    }
  };
  auto loadB = [&](int k0) {
    if (TRANSB) {
      const float* brow = B + (size_t)(bm + brT) * K + k0 + bcT;
      #pragma unroll
      for (int i = 0; i < BRF; ++i) brf[i] = *(const float4*)&brow[i * 4];
    } else {
      #pragma unroll
      for (int i = 0; i < BRF; ++i) {
        int idx = tid + i * 256;
        int kk = (BN == 128) ? (idx >> 5) : (idx >> 4);
        int c4 = (BN == 128) ? ((idx & 31) * 4) : ((idx & 15) * 4);
        brf[i] = *(const float4*)&B[(size_t)(k0 + kk) * M + bm + c4];
      }
    }
  };
  auto store = [&](int buf) {
    if (abf) {
      #pragma unroll
      for (int i = 0; i < ARB; ++i) *(bf16x8*)&Al[buf][sr][sc + i * 8] = arb[i];
    } else {
      #pragma unroll
      for (int i = 0; i < ARF; ++i) {
        float4 v = arf[i];
        short4v s; s[0] = f2bf(v.x); s[1] = f2bf(v.y); s[2] = f2bf(v.z); s[3] = f2bf(v.w);
        *(short4v*)&Al[buf][sr][sc + i * 4] = s;
      }
    }
    if (TRANSB) {
      #pragma unroll
      for (int i = 0; i < BRF; ++i) {
        float4 v = brf[i];
        short4v s; s[0] = f2bf(v.x); s[1] = f2bf(v.y); s[2] = f2bf(v.z); s[3] = f2bf(v.w);
        *(short4v*)&Bl[buf][brT][bcT + i * 4] = s;
      }
    } else {
      #pragma unroll
      for (int i = 0; i < BRF; ++i) {
        int idx = tid + i * 256;
        int kk = (BN == 128) ? (idx >> 5) : (idx >> 4);
        int c4 = (BN == 128) ? ((idx & 31) * 4) : ((idx & 15) * 4);
        float4 v = brf[i];
        Bl[buf][c4 + 0][kk] = f2bf(v.x);
        Bl[buf][c4 + 1][kk] = f2bf(v.y);
        Bl[buf][c4 + 2][kk] = f2bf(v.z);
        Bl[buf][c4 + 3][kk] = f2bf(v.w);
      }
    }
  };

  loadA(0); loadB(0); store(0);
  __syncthreads();
  const int nk = K / BK;
  for (int s = 0; s < nk; ++s) {
    const int cur = s & 1;
    if (s + 1 < nk) { loadA((s + 1) * BK); loadB((s + 1) * BK); }
    #pragma unroll
    for (int kh = 0; kh < BK / 32; ++kh) {
      bf16x8 af[4], bfr[NI];
      #pragma unroll
      for (int mi = 0; mi < 4; ++mi)
        af[mi] = *(bf16x8*)&Al[cur][wm + mi * 16 + fr][kh * 32 + fg * 8];
      #pragma unroll
      for (int ni = 0; ni < NI; ++ni)
        bfr[ni] = *(bf16x8*)&Bl[cur][wn + ni * 16 + fr][kh * 32 + fg * 8];
      #pragma unroll
      for (int mi = 0; mi < 4; ++mi)
        #pragma unroll
        for (int ni = 0; ni < NI; ++ni)
          acc[mi][ni] = __builtin_amdgcn_mfma_f32_16x16x32_bf16(af[mi], bfr[ni], acc[mi][ni], 0, 0, 0);
    }
    if (s + 1 < nk) store(cur ^ 1);
    __syncthreads();
  }

  bool done = false;
  if constexpr (BN == 128) {
    if (z == vtrans_z) {
      done = true;
      // V-tiled: [bh][kt][d=64][k=64], granule16 col ^= (d&7). uint2 spans k..k+3.
      #pragma unroll
      for (int mi = 0; mi < 4; ++mi) {
        int nbase = bn + wm + mi * 16 + fg * 4;
        int b_  = nbase >> TPB_BITS;
        int key = nbase & ((1 << TPB_BITS) - 1);
        int kt  = key >> 6, kin = key & 63;
        #pragma unroll
        for (int ni = 0; ni < 4; ++ni) {
          int col = bm + wn + ni * 16 + fr;
          int h_ = col >> 6, dh = col & 63;
          uint2 u;
          u.x = cvtpk(acc[mi][ni][0], acc[mi][ni][1]);
          u.y = cvtpk(acc[mi][ni][2], acc[mi][ni][3]);
          size_t off = ((((size_t)(b_ * H_ + h_) * NKT_) + kt) << 12)
                     + dh * 64 + (((kin >> 3) ^ (dh & 7)) << 3) + (kin & 7);
          *(uint2*)&((short*)Cv)[off] = u;
        }
      }
    } else if (z == ktile_z) {
      done = true;
      // K-tiled: [bh][kt][k=64][d=64], granule16 col ^= (k&3)|((k>>3)&1)<<2.
      #pragma unroll
      for (int mi = 0; mi < 4; ++mi) {
        #pragma unroll
        for (int reg = 0; reg < 4; ++reg) {
          int tok = bn + wm + mi * 16 + fg * 4 + reg;
          int b_  = tok >> TPB_BITS;
          int key = tok & ((1 << TPB_BITS) - 1);
          int kt  = key >> 6, kin = key & 63;
          int fk  = (kin & 3) | (((kin >> 3) & 1) << 2);
          size_t tb = ((((size_t)(b_ * H_) * NKT_) + kt) << 12) + kin * 64;
          #pragma unroll
          for (int ni = 0; ni < 4; ++ni) {
            int col = bm + wn + ni * 16 + fr;
            int h_ = col >> 6, dh = col & 63;
            size_t off = tb + (((size_t)h_ * NKT_) << 12)
                       + (((dh >> 3) ^ fk) << 3) + (dh & 7);
            ((short*)Cv)[off] = f2bf(acc[mi][ni][reg]);
          }
        }
      }
    }
  }
  if (!done) {
    const float cs = (z == qscale_z) ? SCL2E_ : 1.f;
    #pragma unroll
    for (int mi = 0; mi < 4; ++mi) {
      #pragma unroll
      for (int reg = 0; reg < 4; ++reg) {
        size_t rowbase = (size_t)(bn + wm + mi * 16 + fg * 4 + reg) * M + bm + wn;
        #pragma unroll
        for (int ni = 0; ni < NI; ++ni) {
          float v = acc[mi][ni][reg] * cs;
          if (RELU) v = fmaxf(v, 0.f);
          if (CBF16) ((short*)Cv)[rowbase + ni * 16 + fr] = f2bf(v);
          else       ((float*)Cv)[rowbase + ni * 16 + fr] = v;
        }
      }
    }
  }
}

// ---------------------------------------------------------------------------
// bf16 MFMA flash attention, P-in-registers, pre-scaled Q (log2 domain).
// Per-tile clear-flag skips bias on unmasked tiles; psum pairwise tree.
// K/V via global_load_lds from pre-swizzled tiles, double-buffered, ONE
// barrier per tile. Grid (bh, by); CAUSAL: qt = last - by (heavy first, R9).
// ---------------------------------------------------------------------------
template<bool CAUSAL>
__global__ __launch_bounds__(256) void attn_mfma(const short* __restrict__ Q,
                                                 const short* __restrict__ KT,
                                                 const short* __restrict__ VT,
                                                 const float* __restrict__ bias,
                                                 const float* __restrict__ flags,
                                                 short* __restrict__ O,
                                                 int T, int Lk) {
  __shared__ short Kl[2][64][64];
  __shared__ short Vl[2][64][64];
  const int tid = threadIdx.x;
  const int l   = tid & 63;
  const int w   = tid >> 6;
  const int bh  = blockIdx.x;
  const int b   = bh >> 2;
  const int h   = bh & 3;
  const int r   = l & 15;
  const int g   = l >> 4;

  const short* Ktile = KT + (((size_t)bh * (Lk >> 6)) << 12);
  const short* Vtile = VT + (((size_t)bh * (Lk >> 6)) << 12);
  const float* brow  = bias + (size_t)b * Lk;
  const float* bfl   = flags + b * NKT_;

  const int qt  = CAUSAL ? ((T >> 6) - 1 - (int)blockIdx.y) : (int)blockIdx.y;
  const int nkt = CAUSAL ? (qt + 1) : (Lk >> 6);

  bf16x8 qf[2];
  {
    const short* qrow = Q + ((size_t)(b * T + qt * 64 + w * 16 + r)) * D_ + h * DH_;
    qf[0] = *(const bf16x8*)&qrow[g * 8];
    qf[1] = *(const bf16x8*)&qrow[32 + g * 8];
  }

  float m = -1e30f, ls = 0.f;
  f32x4 acc[4];
  #pragma unroll
  for (int dt = 0; dt < 4; ++dt) acc[dt] = (f32x4){0.f, 0.f, 0.f, 0.f};

  auto stage = [&](int kt, int bb) {
    const short* ks = Ktile + ((size_t)kt << 12) + w * 1024 + (size_t)l * 8;
    const short* vs = Vtile + ((size_t)kt << 12) + w * 1024 + (size_t)l * 8;
    char* kd = (char*)&Kl[bb][0][0] + w * 2048;
    char* vd = (char*)&Vl[bb][0][0] + w * 2048;
    gl_lds16(ks,       kd);
    gl_lds16(ks + 512, kd + 1024);
    gl_lds16(vs,       vd);
    gl_lds16(vs + 512, vd + 1024);
  };

  stage(0, 0);
  __syncthreads();

  const int rx = r & 7;
  // QK^T row base for sub-tile st: row' = 32*(st>>1) + 4*(st&1) + 8*(r>>2) + (r&3)
  const int rowp = 8 * (r >> 2) + (r & 3);
  for (int kt = 0; kt < nkt; ++kt) {
    const int buf = kt & 1;
    if (kt + 1 < nkt) stage(kt + 1, buf ^ 1);

    const char* kb = (const char*)&Kl[buf][0][0];
    const char* vb = (const char*)&Vl[buf][0][0];

    // ---- swapped QK^T, k-remapped sub-tiles (Q pre-scaled: sfr is log2-domain)
    f32x4 sfr[4];
    #pragma unroll
    for (int st = 0; st < 4; ++st) sfr[st] = (f32x4){0.f, 0.f, 0.f, 0.f};
    __builtin_amdgcn_s_setprio(1);
    #pragma unroll
    for (int st = 0; st < 4; ++st) {
      const int rowk = 32 * (st >> 1) + 4 * (st & 1) + rowp;
      #pragma unroll
      for (int kh = 0; kh < 2; ++kh) {
        bf16x8 kf = *(const bf16x8*)(kb + rowk * 128 + (((kh * 4 + g) ^ rx) << 4));
        sfr[st] = __builtin_amdgcn_mfma_f32_16x16x32_bf16(kf, qf[kh], sfr[st], 0, 0, 0);
      }
    }
    __builtin_amdgcn_s_setprio(0);

    // ---- bias only when tile has masked keys (wave-uniform branch) ----
    float sc[4][4];
    if (bfl[kt] != 0.f) {
      #pragma unroll
      for (int st = 0; st < 4; ++st) {
        float4 mv = *(const float4*)&brow[kt * 64 + 32 * (st >> 1) + 4 * (st & 1) + 8 * g];
        sc[st][0] = sfr[st][0] + mv.x;
        sc[st][1] = sfr[st][1] + mv.y;
        sc[st][2] = sfr[st][2] + mv.z;
        sc[st][3] = sfr[st][3] + mv.w;
      }
    } else {
      #pragma unroll
      for (int st = 0; st < 4; ++st)
        #pragma unroll
        for (int reg = 0; reg < 4; ++reg) sc[st][reg] = sfr[st][reg];
    }
    if (CAUSAL && kt == qt) {
      #pragma unroll
      for (int st = 0; st < 4; ++st)
        #pragma unroll
        for (int reg = 0; reg < 4; ++reg)
          if (32 * (st >> 1) + 4 * (st & 1) + 8 * g + reg > w * 16 + r)
            sc[st][reg] = -1e30f;
    }

    // ---- row max via max3 triples ----
    float t0 = fmaxf(fmaxf(sc[0][0], sc[0][1]), sc[0][2]);
    float t1 = fmaxf(fmaxf(sc[0][3], sc[1][0]), sc[1][1]);
    float t2 = fmaxf(fmaxf(sc[1][2], sc[1][3]), sc[2][0]);
    float t3 = fmaxf(fmaxf(sc[2][1], sc[2][2]), sc[2][3]);
    float t4 = fmaxf(fmaxf(sc[3][0], sc[3][1]), sc[3][2]);
    float tm = fmaxf(fmaxf(fmaxf(t0, t1), fmaxf(t2, t3)), fmaxf(t4, sc[3][3]));
    tm = fmaxf(tm, __shfl_xor(tm, 16));
    tm = fmaxf(tm, __shfl_xor(tm, 32));
    const int need = __any(tm - m > 8.f);
    float mnew = need ? fmaxf(m, tm) : m;
    float pe[4][4];
    #pragma unroll
    for (int st = 0; st < 4; ++st)
      #pragma unroll
      for (int reg = 0; reg < 4; ++reg)
        pe[st][reg] = EXP2F(sc[st][reg] - mnew);
    // pairwise-tree psum (short dependency chain)
    float ps0 = (pe[0][0] + pe[0][1]) + (pe[0][2] + pe[0][3]);
    float ps1 = (pe[1][0] + pe[1][1]) + (pe[1][2] + pe[1][3]);
    float ps2 = (pe[2][0] + pe[2][1]) + (pe[2][2] + pe[2][3]);
    float ps3 = (pe[3][0] + pe[3][1]) + (pe[3][2] + pe[3][3]);
    float psum = (ps0 + ps1) + (ps2 + ps3);
    psum += __shfl_xor(psum, 16);
    psum += __shfl_xor(psum, 32);

    // ---- P -> A-frag entirely in registers ----
    union { unsigned u[4]; bf16x8 v; } pa, pb;
    pa.u[0] = cvtpk(pe[0][0], pe[0][1]);
    pa.u[1] = cvtpk(pe[0][2], pe[0][3]);
    pa.u[2] = cvtpk(pe[1][0], pe[1][1]);
    pa.u[3] = cvtpk(pe[1][2], pe[1][3]);
    pb.u[0] = cvtpk(pe[2][0], pe[2][1]);
    pb.u[1] = cvtpk(pe[2][2], pe[2][3]);
    pb.u[2] = cvtpk(pe[3][0], pe[3][1]);
    pb.u[3] = cvtpk(pe[3][2], pe[3][3]);

    if (need) {
      float alpha = EXP2F(m - mnew);
      ls = ls * alpha + psum;
      m = mnew;
      float af[4];
      #pragma unroll
      for (int reg = 0; reg < 4; ++reg) af[reg] = __shfl(alpha, g * 4 + reg);
      #pragma unroll
      for (int dt = 0; dt < 4; ++dt)
        #pragma unroll
        for (int reg = 0; reg < 4; ++reg) acc[dt][reg] *= af[reg];
    } else {
      ls += psum;
    }

    // ---- PV ----
    __builtin_amdgcn_s_setprio(1);
    #pragma unroll
    for (int kh = 0; kh < 2; ++kh) {
      bf16x8 pf = (kh == 0) ? pa.v : pb.v;
      #pragma unroll
      for (int dt = 0; dt < 4; ++dt) {
        bf16x8 vf = *(const bf16x8*)(vb + (dt * 16 + r) * 128 + (((kh * 4 + g) ^ rx) << 4));
        acc[dt] = __builtin_amdgcn_mfma_f32_16x16x32_bf16(pf, vf, acc[dt], 0, 0, 0);
      }
    }
    __builtin_amdgcn_s_setprio(0);

    __syncthreads();   // drains vmcnt (staged tile kt+1) + all reads of buf done
  }

  float inv = (ls > 0.f) ? (1.f / ls) : 0.f;
  float invf[4];
  #pragma unroll
  for (int reg = 0; reg < 4; ++reg) invf[reg] = __shfl(inv, g * 4 + reg);
  #pragma unroll
  for (int reg = 0; reg < 4; ++reg) {
    short* orow = O + ((size_t)(b * T + qt * 64 + w * 16 + g * 4 + reg)) * D_ + h * DH_;
    #pragma unroll
    for (int dt = 0; dt < 4; ++dt)
      orow[dt * 16 + r] = f2bf(acc[dt][reg] * invf[reg]);
  }
}

// ---------------------------------------------------------------------------
// out[row] = R[row] + LayerNorm(F[row]) * g + b   (row length 256, F bf16)
// ---------------------------------------------------------------------------
template<bool RBF16, bool OBF16>
__global__ __launch_bounds__(256) void ln_res(const short* __restrict__ F,
                                              const void* __restrict__ Rv,
                                              const float* __restrict__ g,
                                              const float* __restrict__ bt,
                                              void* __restrict__ outv) {
  const int lane = threadIdx.x & 63;
  const int wid  = threadIdx.x >> 6;
  const size_t row  = (size_t)blockIdx.x * 4 + wid;
  const size_t base = row * 256 + (size_t)lane * 4;
  short4v fv = *(const short4v*)&F[base];
  float vx = bf2f(fv[0]), vy = bf2f(fv[1]), vz = bf2f(fv[2]), vw = bf2f(fv[3]);
  float s = vx + vy + vz + vw;
  #pragma unroll
  for (int o = 32; o >= 1; o >>= 1) s += __shfl_xor(s, o);
  float mu = s * (1.f / 256.f);
  float dx = vx - mu, dy = vy - mu, dz = vz - mu, dw = vw - mu;
  float vr = dx * dx + dy * dy + dz * dz + dw * dw;
  #pragma unroll
  for (int o = 32; o >= 1; o >>= 1) vr += __shfl_xor(vr, o);
  float rstd = rsqrtf(vr * (1.f / 256.f) + 1e-5f);
  float4 g4 = *(const float4*)&g[lane * 4];
  float4 b4 = *(const float4*)&bt[lane * 4];
  float rx, ry, rz, rw;
  if (RBF16) {
    short4v r4 = *(const short4v*)&((const short*)Rv)[base];
    rx = bf2f(r4[0]); ry = bf2f(r4[1]); rz = bf2f(r4[2]); rw = bf2f(r4[3]);
  } else {
    float4 r4 = *(const float4*)&((const float*)Rv)[base];
    rx = r4.x; ry = r4.y; rz = r4.z; rw = r4.w;
  }
  float ox = fmaf(dx * rstd, g4.x, b4.x) + rx;
  float oy = fmaf(dy * rstd, g4.y, b4.y) + ry;
  float oz = fmaf(dz * rstd, g4.z, b4.z) + rz;
  float ow = fmaf(dw * rstd, g4.w, b4.w) + rw;
  if (OBF16) {
    uint2 u; u.x = cvtpk(ox, oy); u.y = cvtpk(oz, ow);
    *(uint2*)&((short*)outv)[base] = u;
  } else {
    *(float4*)&((float*)outv)[base] = make_float4(ox, oy, oz, ow);
  }
}

extern "C" void kernel_launch(void* const* d_in, const int* in_sizes, int n_in,
                              void* d_out, int out_size, void* d_ws, size_t ws_size,
                              hipStream_t stream) {
  const float* Xt    = (const float*)d_in[0];
  const float* oMask = (const float*)d_in[1];
  const float* Xe    = (const float*)d_in[2];
  const float* iMask = (const float*)d_in[3];
  const float* Wq1   = (const float*)d_in[4];
  const float* Wk1   = (const float*)d_in[5];
  const float* Wv1   = (const float*)d_in[6];
  const float* Wo1   = (const float*)d_in[7];
  const float* Wq2   = (const float*)d_in[8];
  const float* Wk2   = (const float*)d_in[9];
  const float* Wv2   = (const float*)d_in[10];
  const float* Wo2   = (const float*)d_in[11];
  const float* W1    = (const float*)d_in[12];
  const float* W2    = (const float*)d_in[13];
  const float* g1    = (const float*)d_in[14];
  const float* b1    = (const float*)d_in[15];
  const float* g2    = (const float*)d_in[16];
  const float* b2    = (const float*)d_in[17];
  const float* g3    = (const float*)d_in[18];
  const float* b3    = (const float*)d_in[19];

  const int B = 16, T = 1024, S = 1024;
  const int NT = B * T;
  const size_t SZ = (size_t)NT * 256;   // fp32-sized slot

  float* ws = (float*)d_ws;
  float* s0 = ws;                // Q bf16 / FFN H bf16 (spans s0..s1) / Wo out bf16
  float* s1 = ws + SZ;           // K tiled bf16
  float* s2 = ws + 2 * SZ;       // V tiled bf16
  float* s3 = ws + 3 * SZ;       // attn out bf16 (first 8MB) + bias/flags tail
  float* s4 = ws + 4 * SZ;       // Xa bf16 / F bf16
  float* s5 = ws + 5 * SZ;       // Xb bf16
  short* b_s0 = (short*)s0; short* b_s1 = (short*)s1; short* b_s2 = (short*)s2;
  short* b_s3 = (short*)s3; short* b_s4 = (short*)s4; short* b_s5 = (short*)s5;
  float* biasS = s3 + 3 * (SZ / 4);          // 12MB into s3 slot
  float* biasC = biasS + B * S;
  float* flagS = biasC + B * S;
  float* flagC = flagS + B * NKT_;

  dim3 blk(256);
  dim3 gQKV(NT / 128, 2, 3);     // fused q/k/v (BK=32 -> 4 blocks/CU)
  dim3 gS64(NT / 128, 4, 1);     // BN=64 singles -> 512 blocks
  dim3 gF1(NT / 128, 8, 1);      // FFN1 (BK=32 -> fully resident)
  dim3 gA(B * H_, T / 64);       // one q-strip per block, 1024 blocks = 4/CU

  mask_bias<<<64, blk, 0, stream>>>(oMask, iMask, biasS, biasC, flagS, flagC, B * T);

  // ---- self-attention block ----
  gemm_mfma<128, 32, false, true, false, true><<<gQKV, blk, 0, stream>>>(
      Xt, Xt, Xt, Wq1, Wk1, Wv1, s0, s1, s2, NT, 256, 256, 2, 1, -1, 0);
  attn_mfma<true><<<gA, blk, 0, stream>>>(b_s0, b_s1, b_s2, biasS, flagS, b_s3, T, T);
  gemm_mfma<64, 64, true, true, false, true><<<gS64, blk, 0, stream>>>(
      s3, s3, s3, Wo1, Wo1, Wo1, s0, s0, s0, NT, 256, 256, -1, -1, -1, -1);
  ln_res<false, true><<<NT / 4, blk, 0, stream>>>(b_s0, Xt, g1, b1, b_s4);

  // ---- cross-attention block (Q2 merged into K/V fused launch) ----
  gemm_mfma<128, 32, false, true, false, true><<<gQKV, blk, 0, stream>>>(
      s4, Xe, Xe, Wq2, Wk2, Wv2, s0, s1, s2, NT, 256, 256, 2, 1, 0, 0);
  attn_mfma<false><<<gA, blk, 0, stream>>>(b_s0, b_s1, b_s2, biasC, flagC, b_s3, T, S);
  gemm_mfma<64, 64, true, false, false, true><<<gS64, blk, 0, stream>>>(
      s3, s3, s3, Wo2, Wo2, Wo2, s0, s0, s0, NT, 256, 256, -1, -1, -1, -1);
  ln_res<true, true><<<NT / 4, blk, 0, stream>>>(b_s0, b_s4, g2, b2, b_s5);

  // ---- FFN ----  (H bf16 spans s0..s1)
  gemm_mfma<128, 32, true, true, true, true><<<gF1, blk, 0, stream>>>(
      s5, s5, s5, W1, W1, W1, s0, s0, s0, NT, 256, 1024, -1, -1, -1, -1);
  gemm_mfma<64, 64, true, true, true, true><<<gS64, blk, 0, stream>>>(
      s0, s0, s0, W2, W2, W2, s4, s4, s4, NT, 1024, 256, -1, -1, -1, -1);
  ln_res<true, false><<<NT / 4, blk, 0, stream>>>(b_s4, b_s5, g3, b3, (float*)d_out);
}